// Round 8
// baseline (434.479 us; speedup 1.0000x reference)
//
#include <hip/hip_runtime.h>
#include <cmath>

// ---------------------------------------------------------------------------
// Round 8 (= round 7 + compile fix): 3-stage software-pipelined GEMM.
//  - BK=32, three 16KB LDS buffers (48KB -> 3 blocks/CU, 12 waves).
//  - per-wave 4 global_load_lds per tile; barrier = s_waitcnt vmcnt(4)
//    lgkmcnt(0); s_barrier  -> tile loads get a full iteration to land
//    (2 newest tiles stay in flight; 3 buffers keep reader/writer disjoint).
//  - K-loop fully unrolled; global offsets folded via pointer arithmetic
//    (builtin's offset arg must be a literal constant -> pass 0 and let the
//    constant GEP fold into the instruction immediate after unrolling).
//  - 4-way XOR swizzle (quad ^ (row>>1)&3) keeps b128 fragment reads
//    bank-uniform with 64-B LDS rows.
// Arena (inside attention output region): slot r (16 KB) =
//   [ G-bf16 row r : 8 KB | input bf16 chunks 4r..4r+3 : 8 KB ]
// chunk order: 0..N-1 step, N..N+M-1 modal, N+M..N+2M-1 negs.
// ---------------------------------------------------------------------------

#define WAVE 64

typedef __bf16 bf16x8_t __attribute__((ext_vector_type(8)));
typedef __bf16 bf16x4_t __attribute__((ext_vector_type(4)));
typedef float f32x4_t __attribute__((ext_vector_type(4)));

__device__ __forceinline__ float wave_reduce_sum(float v) {
#pragma unroll
    for (int o = 32; o > 0; o >>= 1) v += __shfl_down(v, o, WAVE);
    return v;
}
__device__ __forceinline__ float wave_reduce_max(float v) {
#pragma unroll
    for (int o = 32; o > 0; o >>= 1) v = fmaxf(v, __shfl_down(v, o, WAVE));
    return v;
}
__device__ __forceinline__ float wave_reduce_min(float v) {
#pragma unroll
    for (int o = 32; o > 0; o >>= 1) v = fminf(v, __shfl_down(v, o, WAVE));
    return v;
}

// monotone float <-> uint map for atomicMax on floats of any sign
__device__ __forceinline__ unsigned enc_f(float f) {
    unsigned u = __float_as_uint(f);
    return (u & 0x80000000u) ? ~u : (u | 0x80000000u);
}
__device__ __forceinline__ float dec_f(unsigned e) {
    unsigned u = (e & 0x80000000u) ? (e & 0x7fffffffu) : ~e;
    return __uint_as_float(u);
}

// ---------------- convert fp32 -> bf16 chunks + inverse norms --------------
__global__ __launch_bounds__(256)
void convert_norms_kernel(const float* __restrict__ step,
                          const float* __restrict__ modal,
                          const float* __restrict__ negs,
                          char* __restrict__ arena,
                          float* __restrict__ ina, float* __restrict__ inb,
                          float* __restrict__ inn,
                          unsigned* __restrict__ negmax_u, int N, int M) {
    const int tid = threadIdx.x, lane = tid & 63, wv = tid >> 6;
    const int b = blockIdx.x * 4 + wv;
    const float* src;
    if (b < N)          src = step  + (size_t)b * 1024;
    else if (b < N + M) src = modal + (size_t)(b - N) * 1024;
    else                src = negs  + (size_t)(b - N - M) * 1024;

    char* cb = arena + (((size_t)(b >> 2)) << 14) + ((size_t)(b & 3) << 11) + 8192;
    float s = 0.0f;
#pragma unroll
    for (int q = 0; q < 4; q++) {
        const int idx = lane + q * 64;
        const float4 v = ((const float4*)src)[idx];
        bf16x4_t o;
        o[0] = (__bf16)v.x; o[1] = (__bf16)v.y;
        o[2] = (__bf16)v.z; o[3] = (__bf16)v.w;
        *(bf16x4_t*)(cb + (size_t)idx * 8) = o;
        s += v.x * v.x + v.y * v.y + v.z * v.z + v.w * v.w;
    }
    s = wave_reduce_sum(s);
    if (lane == 0) {
        const float inv = 1.0f / fmaxf(sqrtf(s), 1e-8f);
        if (b < N)          { ina[b] = inv; negmax_u[b] = 0u; }
        else if (b < N + M) inb[b - N] = inv;
        else                inn[b - N - M] = inv;
    }
}

// ---------------- 3-stage pipelined fused bf16 MFMA GEMM -------------------
// offset folded into the pointer (builtin offset arg must be literal 0)
#define GLD16(g, l)                                                       \
    __builtin_amdgcn_global_load_lds(                                     \
        (const __attribute__((address_space(1))) void*)(g),               \
        (__attribute__((address_space(3))) void*)(l), 16, 0, 0)

__global__ __launch_bounds__(256, 3)
void gemm_fused_kernel(char* __restrict__ arena, int N, int M,
                       const float* __restrict__ inv_nn,
                       unsigned* __restrict__ negmax_u) {
    __shared__ __bf16 smA[3][128 * 32];   // 3 x 8 KB
    __shared__ __bf16 smB[3][128 * 32];   // 3 x 8 KB

    // supertile swizzle: 16 bm-blocks x 8 bn-blocks per supertile
    const int lin = blockIdx.x;            // 0..4095
    const int st  = lin >> 7;
    const int r128 = lin & 127;
    const int bxi = (st & 7) * 8 + (r128 & 7);
    const int byi = (st >> 3) * 16 + (r128 >> 3);
    const int bm = byi * 128, bn = bxi * 128;

    const int t = threadIdx.x, w = t >> 6, lane = t & 63;
    const int lane16 = lane & 15, lq = lane >> 4;
    const int wm = (w & 1) * 64, wn = (w >> 1) * 64;

    // ---- staging: waves 0-1 -> A halves, waves 2-3 -> B halves ----
    // GLD16 #g covers tile rows wrow+g*16 .. +15; lane -> row (lane>>2),
    // LDS quad (lane&3). Global quad = (lane&3) ^ ((row>>1)&3)  [swizzle].
    const int s_is_b = w >> 1;
    const int wrow   = (w & 1) * 64;
    const int rl = lane >> 2, ql = lane & 3;
    const int o_sw = ql ^ ((rl >> 1) & 3);
    const int cbase = (s_is_b ? (N + bn) : bm) + wrow;

    const char* ga[4];
#pragma unroll
    for (int g = 0; g < 4; g++) {
        const int c = cbase + g * 16 + rl;
        ga[g] = arena + (((size_t)(c >> 2)) << 14) + ((size_t)(c & 3) << 11)
                + 8192 + (size_t)o_sw * 16;
    }

    f32x4_t acc[4][4];
#pragma unroll
    for (int i = 0; i < 4; i++)
#pragma unroll
        for (int j = 0; j < 4; j++) acc[i][j] = (f32x4_t){0.f, 0.f, 0.f, 0.f};

    // fragment read offsets (bf16 elems), i-invariant swizzle
    const int fsw = (lane16 >> 1) & 3;
    const int a_base = (wm + lane16) * 32 + (lq ^ fsw) * 8;
    const int b_base = (wn + lane16) * 32 + (lq ^ fsw) * 8;

    // prologue: tile 0 -> buf 0, tile 1 -> buf 1  (vmcnt = 8)
#pragma unroll
    for (int g = 0; g < 4; g++) {
        __bf16* d0 = (s_is_b ? smB[0] : smA[0]) + wrow * 32 + g * 512;
        GLD16(ga[g], d0);
    }
#pragma unroll
    for (int g = 0; g < 4; g++) {
        __bf16* d1 = (s_is_b ? smB[1] : smA[1]) + wrow * 32 + g * 512;
        GLD16(ga[g] + 64, d1);
    }

#pragma unroll
    for (int it = 0; it < 32; ++it) {
        // wait my tile-it loads (keep newest 4 in flight), sync block.
        // lgkmcnt(0): my prev-iter ds_reads done -> safe for others' GLD16s.
        if (it < 31)
            asm volatile("s_waitcnt vmcnt(4) lgkmcnt(0)\n\ts_barrier" ::: "memory");
        else
            asm volatile("s_waitcnt vmcnt(0) lgkmcnt(0)\n\ts_barrier" ::: "memory");

        const int cur = it % 3;

        // issue tile it+2 into buf (it+2)%3 (disjoint from cur and it+1)
        if (it < 30) {
            const int nx = (it + 2) % 3;
            __bf16* d = (s_is_b ? smB[nx] : smA[nx]) + wrow * 32;
#pragma unroll
            for (int g = 0; g < 4; g++)
                GLD16(ga[g] + (it + 2) * 64, d + g * 512);
        }

        bf16x8_t af[4], bf[4];
#pragma unroll
        for (int i = 0; i < 4; i++)
            af[i] = *(const bf16x8_t*)&smA[cur][a_base + i * 512];
#pragma unroll
        for (int j = 0; j < 4; j++)
            bf[j] = *(const bf16x8_t*)&smB[cur][b_base + j * 512];

#pragma unroll
        for (int i = 0; i < 4; i++)
#pragma unroll
            for (int j = 0; j < 4; j++)
                acc[i][j] = __builtin_amdgcn_mfma_f32_16x16x32_bf16(
                    af[i], bf[j], acc[i][j], 0, 0, 0);
    }

    // C/D layout (16x16x32): col = lane16, row = lq*4 + reg
    if (bn < M) {
#pragma unroll
        for (int i = 0; i < 4; i++) {
#pragma unroll
            for (int r = 0; r < 4; r++) {
                const int grow = bm + wm + i * 16 + lq * 4 + r;
                __bf16* dst = (__bf16*)(arena + ((size_t)grow << 14)) +
                              bn + wn + lane16;
#pragma unroll
                for (int j = 0; j < 4; j++)
                    dst[j * 16] = (__bf16)acc[i][j][r];
            }
        }
    } else {
        float invn[4];
#pragma unroll
        for (int j = 0; j < 4; j++)
            invn[j] = inv_nn[(bn - M) + wn + j * 16 + lane16];
#pragma unroll
        for (int i = 0; i < 4; i++) {
#pragma unroll
            for (int r = 0; r < 4; r++) {
                float v = acc[i][0][r] * invn[0];
                v = fmaxf(v, acc[i][1][r] * invn[1]);
                v = fmaxf(v, acc[i][2][r] * invn[2]);
                v = fmaxf(v, acc[i][3][r] * invn[3]);
#pragma unroll
                for (int o = 8; o > 0; o >>= 1)
                    v = fmaxf(v, __shfl_xor(v, o, WAVE));
                if (lane16 == 0)
                    atomicMax(&negmax_u[bm + wm + i * 16 + lq * 4 + r], enc_f(v));
            }
        }
    }
}

// ---------------- softmax with fp32 fix-up, coalesced layout ---------------
#define CUT 2.0f
#define MAXCAND 64

__global__ __launch_bounds__(256)
void softmax_fix_kernel(char* __restrict__ arena, const float* __restrict__ step,
                        const float* __restrict__ modal,
                        const float* __restrict__ ina, const float* __restrict__ inb,
                        float* __restrict__ perstep, float* __restrict__ wout,
                        float* __restrict__ attn) {
    const int row = blockIdx.x, tid = threadIdx.x;
    const int lane = tid & 63, wv = tid >> 6;

    __shared__ float srow_s[1024];
    __shared__ float red[8];
    __shared__ float bcast[2];
    __shared__ int   cand[MAXCAND];
    __shared__ float exact[MAXCAND];
    __shared__ int   cnt;

    if (tid == 0) cnt = 0;
    ((float4*)srow_s)[tid] = ((const float4*)(step + (size_t)row * 1024))[tid];

    const __bf16* gb = (const __bf16*)(arena + ((size_t)row << 14));
    float vals[16];
    float invn[16];
#pragma unroll
    for (int g = 0; g < 4; g++) {
        const bf16x4_t v = *(const bf16x4_t*)(gb + g * 1024 + tid * 4);
        const float4 x = *(const float4*)(inb + g * 1024 + tid * 4);
        vals[g * 4 + 0] = (float)v[0]; vals[g * 4 + 1] = (float)v[1];
        vals[g * 4 + 2] = (float)v[2]; vals[g * 4 + 3] = (float)v[3];
        invn[g * 4 + 0] = x.x; invn[g * 4 + 1] = x.y;
        invn[g * 4 + 2] = x.z; invn[g * 4 + 3] = x.w;
    }

    float dmax = -3.4e38f;
#pragma unroll
    for (int j = 0; j < 16; j++) dmax = fmaxf(dmax, vals[j]);
    float wm = wave_reduce_max(dmax);
    if (lane == 0) red[wv] = wm;
    __syncthreads();   // also covers cnt=0 and srow_s
    if (tid == 0) bcast[0] = fmaxf(fmaxf(red[0], red[1]), fmaxf(red[2], red[3]));
    __syncthreads();
    const float m0 = bcast[0];

    const float thr = m0 - CUT;
#pragma unroll
    for (int g = 0; g < 4; g++)
#pragma unroll
        for (int u = 0; u < 4; u++) {
            if (vals[g * 4 + u] >= thr) {
                const int pos = atomicAdd(&cnt, 1);
                if (pos < MAXCAND) cand[pos] = g * 1024 + tid * 4 + u;
            }
        }
    __syncthreads();
    const int nc = min(cnt, MAXCAND);

    for (int i = wv; i < nc; i += 4) {
        const float* mrow = modal + (size_t)cand[i] * 1024;
        float p = 0.0f;
#pragma unroll
        for (int q = 0; q < 16; q++) {
            const int idx = lane + q * 64;
            p = fmaf(srow_s[idx], mrow[idx], p);
        }
        p = wave_reduce_sum(p);
        if (lane == 0) exact[i] = p;
    }
    __syncthreads();

    for (int i = 0; i < nc; i++) {
        const int c = cand[i];
        if (((c & 1023) >> 2) == tid) vals[(c >> 10) * 4 + (c & 3)] = exact[i];
    }

    float dmax2 = -3.4e38f, cmax = -3.4e38f;
#pragma unroll
    for (int j = 0; j < 16; j++) {
        dmax2 = fmaxf(dmax2, vals[j]);
        cmax = fmaxf(cmax, vals[j] * invn[j]);
    }
    float wg = wave_reduce_max(dmax2);
    float wc = wave_reduce_max(cmax);
    if (lane == 0) { red[wv] = wg; red[4 + wv] = wc; }
    __syncthreads();
    if (tid == 0) {
        bcast[0] = fmaxf(fmaxf(red[0], red[1]), fmaxf(red[2], red[3]));
        bcast[1] = fmaxf(fmaxf(red[4], red[5]), fmaxf(red[6], red[7]));
    }
    __syncthreads();
    const float invT = 1.0f / 0.07f;
    const float mlog = bcast[0] * invT;
    const float cmaxAll = bcast[1];

    float evals[16];
    float lsum = 0.0f;
#pragma unroll
    for (int j = 0; j < 16; j++) {
        const float e = __expf(vals[j] * invT - mlog);
        evals[j] = e;
        lsum += e;
    }
    lsum = wave_reduce_sum(lsum);
    __syncthreads();
    if (lane == 0) red[wv] = lsum;
    __syncthreads();
    if (tid == 0) bcast[0] = red[0] + red[1] + red[2] + red[3];
    __syncthreads();
    const float invZ = 1.0f / bcast[0];

    float* arow = attn + (size_t)row * 4096;
    float wacc = 0.0f;
#pragma unroll
    for (int g = 0; g < 4; g++) {
        float4 o;
        const float a0 = evals[g * 4 + 0] * invZ, a1 = evals[g * 4 + 1] * invZ;
        const float a2 = evals[g * 4 + 2] * invZ, a3 = evals[g * 4 + 3] * invZ;
        o.x = a0; o.y = a1; o.z = a2; o.w = a3;
        *(float4*)(arow + g * 1024 + tid * 4) = o;
        wacc += a0 * vals[g * 4 + 0] * invn[g * 4 + 0];
        wacc += a1 * vals[g * 4 + 1] * invn[g * 4 + 1];
        wacc += a2 * vals[g * 4 + 2] * invn[g * 4 + 2];
        wacc += a3 * vals[g * 4 + 3] * invn[g * 4 + 3];
    }
    wacc = wave_reduce_sum(wacc);
    __syncthreads();
    if (lane == 0) red[wv] = wacc;
    __syncthreads();
    if (tid == 0) {
        const float inv_na = ina[row];
        perstep[row] = cmaxAll * inv_na;
        wout[row] = (red[0] + red[1] + red[2] + red[3]) * inv_na;
    }
}

// ---------------- finalize scalars -----------------------------------------
__global__ __launch_bounds__(1024)
void finalize_kernel(const float* __restrict__ perstep, const float* __restrict__ w,
                     const unsigned* __restrict__ negmax_u,
                     const float* __restrict__ ina, float* __restrict__ out,
                     int N, size_t NM) {
    float s_a = 0.0f, s_w = 0.0f, s_n = 0.0f, mn = 3.4e38f;
    for (int i = threadIdx.x; i < N; i += 1024) {
        const float p = perstep[i];
        s_a += p;
        s_w += w[i];
        s_n += dec_f(negmax_u[i]) * ina[i];
        mn = fminf(mn, p);
    }
    s_a = wave_reduce_sum(s_a);
    s_w = wave_reduce_sum(s_w);
    s_n = wave_reduce_sum(s_n);
    mn  = wave_reduce_min(mn);
    __shared__ float ra[16], rw[16], rn[16], rm[16];
    const int lane = threadIdx.x & 63, wv = threadIdx.x >> 6;
    if (lane == 0) { ra[wv] = s_a; rw[wv] = s_w; rn[wv] = s_n; rm[wv] = mn; }
    __syncthreads();
    if (threadIdx.x == 0) {
        float ta = 0, tw = 0, tn = 0, tm = 3.4e38f;
#pragma unroll
        for (int i = 0; i < 16; i++) {
            ta += ra[i]; tw += rw[i]; tn += rn[i]; tm = fminf(tm, rm[i]);
        }
        const float inv = 1.0f / (float)N;
        const float alignment = ta * inv;
        const float weighted  = tw * inv;
        const float neg       = tn * inv;
        const float contrast  = alignment - neg;
        const float margin    = fmaxf(contrast - 0.2f, 0.0f);
        const float overall   = 0.7f * weighted + 0.3f * contrast;
        out[0] = alignment;
        out[1] = weighted;
        float* p = out + 2 + NM;
        p[0] = contrast;
        p[1] = margin;
        p[2] = alignment;   // positive_alignment
        p[3] = neg;
        p[4 + N] = tm;      // min_step_coherence
        p[5 + N] = overall;
    }
}

// ---------------------------------------------------------------------------
extern "C" void kernel_launch(void* const* d_in, const int* in_sizes, int n_in,
                              void* d_out, int out_size, void* d_ws, size_t ws_size,
                              hipStream_t stream) {
    const float* step  = (const float*)d_in[0];
    const float* modal = (const float*)d_in[1];
    const float* negs  = (const float*)d_in[2];
    float* out = (float*)d_out;

    const int K = 1024;
    const int N = in_sizes[0] / K;   // 8192
    const int M = in_sizes[1] / K;   // 4096
    const size_t NM = (size_t)N * (size_t)M;

    float* ina        = (float*)d_ws;          // N
    float* inb        = ina + N;               // M
    float* inn        = inb + M;               // M
    unsigned* negmax  = (unsigned*)(inn + M);  // N
    float* wsum       = (float*)(negmax + N);  // N

    char* arena    = (char*)d_out + 16;
    float* attn    = out + 2;
    float* perstep = out + 2 + NM + 4;

    // 1. convert inputs to bf16 chunks + inverse norms + init atomics
    convert_norms_kernel<<<(N + 2 * M) / 4, 256, 0, stream>>>(
        step, modal, negs, arena, ina, inb, inn, negmax, N, M);

    // 2. 3-stage pipelined fused GEMM (supertile-swizzled 1-D grid)
    const int nblocks = (N / 128) * ((2 * M) / 128);
    gemm_fused_kernel<<<nblocks, 256, 0, stream>>>(arena, N, M, inn, negmax);

    // 3. softmax + exact fp32 fix-up, writes fp32 attention + per-row outs
    softmax_fix_kernel<<<N, 256, 0, stream>>>(arena, step, modal, ina, inb,
                                              perstep, wsum, attn);

    // 4. scalars
    finalize_kernel<<<1, 1024, 0, stream>>>(perstep, wsum, negmax, ina, out, N, NM);
}